// Round 4
// baseline (178.117 us; speedup 1.0000x reference)
//
#include <hip/hip_runtime.h>

// AFM layer, MI355X gfx950.
// out[b] = sum_p attn_p * s_p,  s_p = sum_d x[i,d]x[j,d]p[d]
// R7: latency-bound -> raise TLP: 2 waves/batch. 62us, VALU 56%, MFMA 18%,
// occupancy 37% (~3 waves/SIMD), 0 conflicts, no spill, VGPR 64.
// R8/R9 FAILED (237us): ping-pong pipeline via multi-site lambdas with
// reference outs -> C-frags demoted to scratch (WRITE 221MB). Lesson: keep
// single-lambda loop-local SSA.
// R10 FAILED (79us): sp moved to a 2nd chained MFMA stream. MfmaUtil 29%,
// VALU 40%, no spill — but 27% SLOWER. Lesson: the fdot2 sp-trees were FREE
// (executed in the MFMA shadow); doubling MFMA chains lengthened the body
// tail. The R7 body is the right body.
// R11 (this round): more TLP, shorter per-wave chain. ONE batch per
// 256-thread block (grid 8192, LDS 6.1KB), 4 roles x 6 rotation bodies
// (t=1+6r..6+6r); role 3 adds the 28-pair cleanup. Per-wave bodies 12->6,
// and residency cap rises to 8 blocks/CU (VGPR 64 -> 8 waves/SIMD, LDS
// 6.1KB -> 25 blocks). Body/schedule/reduce = unchanged R7 code.
// LDS: R2's padded stride-76 rows, b64 accesses — MEASURED 0 bank conflicts.
// Pair coverage per batch (25 bodies, 780/800 slots):
//   t=1..15 : 32-rotation (nl,(nl+t)&31) all-valid (prod symmetric);
//   t=16    : half-rotation, nl<16;  t=17..24: uniform rows 32..39;
//   cleanup : 8-triangle of fields 32..39 (28 pairs, closed-form unrank).
// __launch_bounds__(256,4): compiler lands at 64 VGPR (don't perturb; R3's
// (256,8) strangled the allocator -> spill).

typedef _Float16 f16;
typedef f16 f16x2 __attribute__((ext_vector_type(2)));
typedef f16 f16x4 __attribute__((ext_vector_type(4)));
typedef f16 f16x8 __attribute__((ext_vector_type(8)));
typedef float fx16 __attribute__((ext_vector_type(16)));

#define NF 40
#define NB 8192
#define STR 76   // f16 elements per LDS row (152 B) — conflict-free (R2)

union V8 { f16x8 v8; f16x4 v4[2]; f16x2 v2[4]; };

__global__ __launch_bounds__(256, 4) void afm_kernel(
    const float* __restrict__ x,   // [8192,40,64]
    const float* __restrict__ W1,  // [64,32]
    const float* __restrict__ b1,  // [32]
    const float* __restrict__ w2,  // [32]
    const float* __restrict__ p,   // [64]
    float* __restrict__ out)       // [8192]
{
    __shared__ f16 xh[NF * STR];        // 40 x 76 f16 = 6,080 B
    __shared__ float red[4][2];         // [role][aW,aS]

    const int tid  = threadIdx.x;
    const int wid  = tid >> 6;          // role 0..3
    const int lane = tid & 63;
    const int b    = blockIdx.x;

    // ---- stage 1 batch (2560 floats) -> LDS f16, stride-76 rows ----
    const float4* xb = (const float4*)(x + (size_t)b * (NF * 64));
#pragma unroll
    for (int t = 0; t < 2; ++t) {
        int g = t * 256 + tid;                 // granule 0..319 (8 f16 each)
        if (g < 320) {
            float4 v0 = xb[g * 2];
            float4 v1 = xb[g * 2 + 1];
            f16x4 lo = { (f16)v0.x, (f16)v0.y, (f16)v0.z, (f16)v0.w };
            f16x4 hi = { (f16)v1.x, (f16)v1.y, (f16)v1.z, (f16)v1.w };
            int row = g >> 3, gg = g & 7;
            f16* dst = xh + row * STR + gg * 8;
            *(f16x4*)dst = lo;                 // 8B-aligned b64 writes
            *(f16x4*)(dst + 4) = hi;
        }
    }
    __syncthreads();

    const int nl = lane & 31;   // MFMA column / field index base
    const int hh = lane >> 5;   // wave half -> k sub-block + a-row group
    const int h8 = hh * 8;

    // ---- A-frags: W1^T, A[m=a][k=h8+j], d = kt*16 + h8 + j ----
    f16x8 w1f[4];
#pragma unroll
    for (int kt = 0; kt < 4; ++kt)
#pragma unroll
        for (int j = 0; j < 8; ++j)
            w1f[kt][j] = (f16)W1[(kt * 16 + h8 + j) * 32 + nl];

    // ---- p packed to match prod-frag element order (for fdot2) ----
    f16x2 pp[16];
#pragma unroll
    for (int kt = 0; kt < 4; ++kt)
#pragma unroll
        for (int m = 0; m < 4; ++m) {
            f16x2 t2 = { (f16)p[kt * 16 + h8 + 2 * m], (f16)p[kt * 16 + h8 + 2 * m + 1] };
            pp[kt * 4 + m] = t2;
        }

    // ---- b1 as persistent C-frag; w2*log2e packed f16 (exp2 direct) ----
    fx16 b1C;
    f16x2 w2h[8];
#pragma unroll
    for (int r = 0; r < 16; ++r) {
        int a = (r & 3) + 8 * (r >> 2) + 4 * hh;
        b1C[r] = b1[a];
    }
#pragma unroll
    for (int m = 0; m < 8; ++m) {
        int r = 2 * m;
        int a = (r & 3) + 8 * (r >> 2) + 4 * hh;
        f16x2 t2 = { (f16)(w2[a] * 1.44269504f), (f16)(w2[a + 1] * 1.44269504f) };
        w2h[m] = t2;
    }

    // ---- xi frags for row nl ----
    f16x4 xif[8];
    {
        const f16* src = xh + nl * STR + h8;
#pragma unroll
        for (int kt = 0; kt < 4; ++kt) {
            xif[2 * kt]     = *(const f16x4*)(src + kt * 16);
            xif[2 * kt + 1] = *(const f16x4*)(src + kt * 16 + 4);
        }
    }

    float accW = 0.f, accWS = 0.f;

    auto body = [&](const f16x4* xi, int jrow, bool valid) {
        const f16* base = xh + jrow * STR + h8;
        V8 pr[4];
#pragma unroll
        for (int kt = 0; kt < 4; ++kt) {
            f16x4 a0 = *(const f16x4*)(base + kt * 16);       // ds_read_b64
            f16x4 a1 = *(const f16x4*)(base + kt * 16 + 4);
            pr[kt].v4[0] = xi[2 * kt] * a0;                    // v_pk_mul_f16
            pr[kt].v4[1] = xi[2 * kt + 1] * a1;
        }
        // h = W1^T prod + b1 : chain C from persistent b1 frag
        fx16 C = __builtin_amdgcn_mfma_f32_32x32x16_f16(w1f[0], pr[0].v8, b1C, 0, 0, 0);
        C = __builtin_amdgcn_mfma_f32_32x32x16_f16(w1f[1], pr[1].v8, C, 0, 0, 0);
        C = __builtin_amdgcn_mfma_f32_32x32x16_f16(w1f[2], pr[2].v8, C, 0, 0, 0);
        C = __builtin_amdgcn_mfma_f32_32x32x16_f16(w1f[3], pr[3].v8, C, 0, 0, 0);
        // s_p partial: 4 parallel fdot2 trees — free inside the MFMA shadow
        float s0 = 0.f, s1 = 0.f, s2 = 0.f, s3 = 0.f;
#pragma unroll
        for (int m = 0; m < 4; ++m) {
            s0 = __builtin_amdgcn_fdot2(pr[0].v2[m], pp[m],      s0, false);
            s1 = __builtin_amdgcn_fdot2(pr[1].v2[m], pp[4 + m],  s1, false);
            s2 = __builtin_amdgcn_fdot2(pr[2].v2[m], pp[8 + m],  s2, false);
            s3 = __builtin_amdgcn_fdot2(pr[3].v2[m], pp[12 + m], s3, false);
        }
        float sp = (s0 + s1) + (s2 + s3);
        // logit partial: relu(h).(w2*log2e) in packed f16, 2 parallel trees
        const f16x2 z2 = { (f16)0.f, (f16)0.f };
        float l0 = 0.f, l1 = 0.f;
#pragma unroll
        for (int m = 0; m < 8; ++m) {
            f16x2 hm = __builtin_bit_cast(f16x2,
                __builtin_amdgcn_cvt_pkrtz(C[2 * m], C[2 * m + 1]));
            hm = __builtin_elementwise_max(hm, z2);            // v_pk_max_f16
            if (m & 1) l1 = __builtin_amdgcn_fdot2(hm, w2h[m], l1, false);
            else       l0 = __builtin_amdgcn_fdot2(hm, w2h[m], l0, false);
        }
        float l = l0 + l1;
        l  += __shfl_xor(l, 32);    // combine a-halves
        sp += __shfl_xor(sp, 32);   // combine k-halves
        float w = __builtin_amdgcn_exp2f(l);   // max-free softmax (|l| small)
        if (!valid) w = 0.f;
        accW += w;
        accWS = fmaf(w, sp, accWS);
    };

    // role wid: 6 rotation bodies t = 1+6*wid .. 6+6*wid; role 3 + cleanup
    const int tb = 1 + wid * 6;
    for (int t = tb; t < tb + 6; ++t) {
        int jrow = (t <= 16) ? ((nl + t) & 31) : (t + 15);
        bool valid = (t != 16) || (nl < 16);
        body(xif, jrow, valid);
    }
    if (wid == 3) {   // cleanup: 28 pairs among fields 32..39 (lanes nl<28)
        int q = nl < 28 ? nl : 27;
        float disc = 225.0f - 8.0f * (float)q;
        int ii = (int)((15.0f - sqrtf(disc)) * 0.5f);
        if (ii * (15 - ii) / 2 > q) --ii;                 // sqrt 1-ulp fixups
        if ((ii + 1) * (14 - ii) / 2 <= q) ++ii;
        int jj = q - ii * (15 - ii) / 2 + ii + 1;
        int iC = 32 + ii, jC = 32 + jj;                   // pair (iC,jC), iC<jC
        f16x4 xi2[8];
        const f16* src = xh + iC * STR + h8;
#pragma unroll
        for (int kt = 0; kt < 4; ++kt) {
            xi2[2 * kt]     = *(const f16x4*)(src + kt * 16);
            xi2[2 * kt + 1] = *(const f16x4*)(src + kt * 16 + 4);
        }
        body(xi2, jC, nl < 28);
    }

    // reduce across the 32 columns (halves already identical)
#pragma unroll
    for (int m = 16; m >= 1; m >>= 1) {
        accW  += __shfl_xor(accW, m);
        accWS += __shfl_xor(accWS, m);
    }
    if (lane == 0) {
        red[wid][0] = accW;
        red[wid][1] = accWS;
    }
    __syncthreads();
    if (tid == 0) {
        float W = (red[0][0] + red[1][0]) + (red[2][0] + red[3][0]);
        float S = (red[0][1] + red[1][1]) + (red[2][1] + red[3][1]);
        out[b] = S / W;
    }
}

extern "C" void kernel_launch(void* const* d_in, const int* in_sizes, int n_in,
                              void* d_out, int out_size, void* d_ws, size_t ws_size,
                              hipStream_t stream) {
    const float* x  = (const float*)d_in[0];
    const float* W1 = (const float*)d_in[1];
    const float* b1 = (const float*)d_in[2];
    const float* w2 = (const float*)d_in[3];
    const float* p  = (const float*)d_in[4];
    float* out = (float*)d_out;
    dim3 grid(NB), block(256);
    hipLaunchKernelGGL(afm_kernel, grid, block, 0, stream, x, W1, b1, w2, p, out);
}

// Round 5
// 150.107 us; speedup vs baseline: 1.1866x; 1.1866x over previous
//
#include <hip/hip_runtime.h>

// AFM layer, MI355X gfx950.
// out[b] = sum_p attn_p * s_p,  s_p = sum_d x[i,d]x[j,d]p[d]
// R7 (62.8us best): 2 waves/batch, VALU 56%, MFMA 18%, occ 37%, VGPR 64.
// R8/R9 FAILED (237us): multi-site lambdas w/ reference outs -> scratch spill.
// R10 FAILED (79us): sp as 2nd MFMA chain -> lengthened body dep-chain; the
// fdot2 sp-trees were FREE in the MFMA shadow. Keep the R7 body.
// R11 FAILED (87us): 4 waves/batch. Occupancy did NOT move (38.9%) -> residency
// arithmetic does not control it; halving bodies/wave doubled per-CU setup.
// Conclusion: kernel is ISSUE-WORK-bound at ~56% fixed utilization.
//   VALUBusy*cyc*4SIMD ~= waves * (VALU*2 + MFMA*8). Lever: cut total issue
//   work per CU; do not lengthen dependent chains.
// R12 (this round): ONE WAVE OWNS ONE BATCH. block=256 = 4 waves = 4 batches.
//   - setup (w1f/pp/b1C/w2h/xif ~250 instr) amortizes over 25 bodies not 12.5
//     -> per-CU issue work -19% vs R7.
//   - each wave stages its own 6KB LDS slice (320 granules = 5*64 lanes,
//     exact) -> ZERO __syncthreads in the kernel; no cross-wave reduce; no
//     role imbalance (R7 role1 did 13 bodies vs role0's 12).
//   - body = untouched R7 body (proven 64 VGPR, 0 spill, 0 bank conflicts).
//   LDS 4*6080=24,320B -> 6 blocks/CU cap >= observed ~3 residency.
// LDS: R2's padded stride-76 rows, b64 accesses — MEASURED 0 bank conflicts.
// Pair coverage per batch (25 bodies, 780/800 slots):
//   t=1..15 : 32-rotation (nl,(nl+t)&31) all-valid (prod symmetric);
//   t=16    : half-rotation, nl<16;  t=17..24: uniform rows 32..39;
//   cleanup : 8-triangle of fields 32..39 (28 pairs, closed-form unrank).
// __launch_bounds__(256,4): compiler lands ~64 VGPR (R3's (256,8) -> spill).

typedef _Float16 f16;
typedef f16 f16x2 __attribute__((ext_vector_type(2)));
typedef f16 f16x4 __attribute__((ext_vector_type(4)));
typedef f16 f16x8 __attribute__((ext_vector_type(8)));
typedef float fx16 __attribute__((ext_vector_type(16)));

#define NF 40
#define NB 8192
#define STR 76   // f16 elements per LDS row (152 B) — conflict-free (R2)

union V8 { f16x8 v8; f16x4 v4[2]; f16x2 v2[4]; };

__global__ __launch_bounds__(256, 4) void afm_kernel(
    const float* __restrict__ x,   // [8192,40,64]
    const float* __restrict__ W1,  // [64,32]
    const float* __restrict__ b1,  // [32]
    const float* __restrict__ w2,  // [32]
    const float* __restrict__ p,   // [64]
    float* __restrict__ out)       // [8192]
{
    __shared__ f16 xh[4][NF * STR];     // 4 batches x 40 x 76 f16 = 24,320 B

    const int tid  = threadIdx.x;
    const int wid  = tid >> 6;          // wave -> private batch
    const int lane = tid & 63;
    const int b    = blockIdx.x * 4 + wid;

    f16* Xs = &xh[wid][0];

    // ---- per-wave staging: this wave's batch only (2560 floats) ----
    // 320 granules of 8 f16 = 5 iterations x 64 lanes, exact. No barrier
    // needed anywhere: the wave only ever reads its own LDS slice, and
    // intra-wave ds ordering is program order (compiler inserts lgkmcnt).
    const float4* xb = (const float4*)(x + (size_t)b * (NF * 64));
#pragma unroll
    for (int t = 0; t < 5; ++t) {
        int g = t * 64 + lane;                 // granule 0..319 (8 f16 each)
        float4 v0 = xb[g * 2];
        float4 v1 = xb[g * 2 + 1];
        f16x4 lo = { (f16)v0.x, (f16)v0.y, (f16)v0.z, (f16)v0.w };
        f16x4 hi = { (f16)v1.x, (f16)v1.y, (f16)v1.z, (f16)v1.w };
        int row = g >> 3, gg = g & 7;
        f16* dst = Xs + row * STR + gg * 8;
        *(f16x4*)dst = lo;                     // 8B-aligned b64 writes
        *(f16x4*)(dst + 4) = hi;
    }

    const int nl = lane & 31;   // MFMA column / field index base
    const int hh = lane >> 5;   // wave half -> k sub-block + a-row group
    const int h8 = hh * 8;

    // ---- A-frags: W1^T, A[m=a][k=h8+j], d = kt*16 + h8 + j ----
    f16x8 w1f[4];
#pragma unroll
    for (int kt = 0; kt < 4; ++kt)
#pragma unroll
        for (int j = 0; j < 8; ++j)
            w1f[kt][j] = (f16)W1[(kt * 16 + h8 + j) * 32 + nl];

    // ---- p packed to match prod-frag element order (for fdot2) ----
    f16x2 pp[16];
#pragma unroll
    for (int kt = 0; kt < 4; ++kt)
#pragma unroll
        for (int m = 0; m < 4; ++m) {
            f16x2 t2 = { (f16)p[kt * 16 + h8 + 2 * m], (f16)p[kt * 16 + h8 + 2 * m + 1] };
            pp[kt * 4 + m] = t2;
        }

    // ---- b1 as persistent C-frag; w2*log2e packed f16 (exp2 direct) ----
    fx16 b1C;
    f16x2 w2h[8];
#pragma unroll
    for (int r = 0; r < 16; ++r) {
        int a = (r & 3) + 8 * (r >> 2) + 4 * hh;
        b1C[r] = b1[a];
    }
#pragma unroll
    for (int m = 0; m < 8; ++m) {
        int r = 2 * m;
        int a = (r & 3) + 8 * (r >> 2) + 4 * hh;
        f16x2 t2 = { (f16)(w2[a] * 1.44269504f), (f16)(w2[a + 1] * 1.44269504f) };
        w2h[m] = t2;
    }

    // ---- xi frags for row nl ----
    f16x4 xif[8];
    {
        const f16* src = Xs + nl * STR + h8;
#pragma unroll
        for (int kt = 0; kt < 4; ++kt) {
            xif[2 * kt]     = *(const f16x4*)(src + kt * 16);
            xif[2 * kt + 1] = *(const f16x4*)(src + kt * 16 + 4);
        }
    }

    float accW = 0.f, accWS = 0.f;

    auto body = [&](const f16x4* xi, int jrow, bool valid) {
        const f16* base = Xs + jrow * STR + h8;
        V8 pr[4];
#pragma unroll
        for (int kt = 0; kt < 4; ++kt) {
            f16x4 a0 = *(const f16x4*)(base + kt * 16);       // ds_read_b64
            f16x4 a1 = *(const f16x4*)(base + kt * 16 + 4);
            pr[kt].v4[0] = xi[2 * kt] * a0;                    // v_pk_mul_f16
            pr[kt].v4[1] = xi[2 * kt + 1] * a1;
        }
        // h = W1^T prod + b1 : chain C from persistent b1 frag
        fx16 C = __builtin_amdgcn_mfma_f32_32x32x16_f16(w1f[0], pr[0].v8, b1C, 0, 0, 0);
        C = __builtin_amdgcn_mfma_f32_32x32x16_f16(w1f[1], pr[1].v8, C, 0, 0, 0);
        C = __builtin_amdgcn_mfma_f32_32x32x16_f16(w1f[2], pr[2].v8, C, 0, 0, 0);
        C = __builtin_amdgcn_mfma_f32_32x32x16_f16(w1f[3], pr[3].v8, C, 0, 0, 0);
        // s_p partial: 4 parallel fdot2 trees — free inside the MFMA shadow
        float s0 = 0.f, s1 = 0.f, s2 = 0.f, s3 = 0.f;
#pragma unroll
        for (int m = 0; m < 4; ++m) {
            s0 = __builtin_amdgcn_fdot2(pr[0].v2[m], pp[m],      s0, false);
            s1 = __builtin_amdgcn_fdot2(pr[1].v2[m], pp[4 + m],  s1, false);
            s2 = __builtin_amdgcn_fdot2(pr[2].v2[m], pp[8 + m],  s2, false);
            s3 = __builtin_amdgcn_fdot2(pr[3].v2[m], pp[12 + m], s3, false);
        }
        float sp = (s0 + s1) + (s2 + s3);
        // logit partial: relu(h).(w2*log2e) in packed f16, 2 parallel trees
        const f16x2 z2 = { (f16)0.f, (f16)0.f };
        float l0 = 0.f, l1 = 0.f;
#pragma unroll
        for (int m = 0; m < 8; ++m) {
            f16x2 hm = __builtin_bit_cast(f16x2,
                __builtin_amdgcn_cvt_pkrtz(C[2 * m], C[2 * m + 1]));
            hm = __builtin_elementwise_max(hm, z2);            // v_pk_max_f16
            if (m & 1) l1 = __builtin_amdgcn_fdot2(hm, w2h[m], l1, false);
            else       l0 = __builtin_amdgcn_fdot2(hm, w2h[m], l0, false);
        }
        float l = l0 + l1;
        l  += __shfl_xor(l, 32);    // combine a-halves
        sp += __shfl_xor(sp, 32);   // combine k-halves
        float w = __builtin_amdgcn_exp2f(l);   // max-free softmax (|l| small)
        if (!valid) w = 0.f;
        accW += w;
        accWS = fmaf(w, sp, accWS);
    };

    // all 24 rotation/uniform bodies + cleanup: this wave's batch, private
    for (int t = 1; t <= 24; ++t) {
        int jrow = (t <= 16) ? ((nl + t) & 31) : (t + 15);
        bool valid = (t != 16) || (nl < 16);
        body(xif, jrow, valid);
    }
    {   // cleanup: 28 pairs among fields 32..39 (lanes nl<28)
        int q = nl < 28 ? nl : 27;
        float disc = 225.0f - 8.0f * (float)q;
        int ii = (int)((15.0f - sqrtf(disc)) * 0.5f);
        if (ii * (15 - ii) / 2 > q) --ii;                 // sqrt 1-ulp fixups
        if ((ii + 1) * (14 - ii) / 2 <= q) ++ii;
        int jj = q - ii * (15 - ii) / 2 + ii + 1;
        int iC = 32 + ii, jC = 32 + jj;                   // pair (iC,jC), iC<jC
        f16x4 xi2[8];
        const f16* src = Xs + iC * STR + h8;
#pragma unroll
        for (int kt = 0; kt < 4; ++kt) {
            xi2[2 * kt]     = *(const f16x4*)(src + kt * 16);
            xi2[2 * kt + 1] = *(const f16x4*)(src + kt * 16 + 4);
        }
        body(xi2, jC, nl < 28);
    }

    // reduce across the 32 columns (halves already identical); lane 0 writes
#pragma unroll
    for (int m = 16; m >= 1; m >>= 1) {
        accW  += __shfl_xor(accW, m);
        accWS += __shfl_xor(accWS, m);
    }
    if (lane == 0) out[b] = accWS / accW;
}

extern "C" void kernel_launch(void* const* d_in, const int* in_sizes, int n_in,
                              void* d_out, int out_size, void* d_ws, size_t ws_size,
                              hipStream_t stream) {
    const float* x  = (const float*)d_in[0];
    const float* W1 = (const float*)d_in[1];
    const float* b1 = (const float*)d_in[2];
    const float* w2 = (const float*)d_in[3];
    const float* p  = (const float*)d_in[4];
    float* out = (float*)d_out;
    dim3 grid(NB / 4), block(256);
    hipLaunchKernelGGL(afm_kernel, grid, block, 0, stream, x, W1, b1, w2, p, out);
}